// Round 1
// baseline (1258.642 us; speedup 1.0000x reference)
//
#include <hip/hip_runtime.h>

#define C 128

// ---- degree: deg[i] = 1 (self loop) + count of edges with col==i ----
__global__ void k_init_deg(float* __restrict__ deg, int N) {
    int i = blockIdx.x * blockDim.x + threadIdx.x;
    if (i < N) deg[i] = 1.0f;
}

__global__ void k_edge_deg(const int* __restrict__ col, float* __restrict__ deg, int E) {
    int e = blockIdx.x * blockDim.x + threadIdx.x;
    if (e < E) unsafeAtomicAdd(&deg[col[e]], 1.0f);
}

// deg -> deg^{-1/2}, in place
__global__ void k_dis(float* __restrict__ deg, int N) {
    int i = blockIdx.x * blockDim.x + threadIdx.x;
    if (i < N) deg[i] = 1.0f / sqrtf(deg[i]);
}

// ---- g[n][o] = (sum_i x[n][i] * W[o][i]) * dis[n] ----
// 128 threads/block (one per output channel), 4 nodes per block.
// Both x rows and W rows are contiguous along i -> float4 loads; x rows staged
// in LDS and read broadcast (same address across all lanes -> conflict-free).
__global__ void k_gemm(const float* __restrict__ x, const float* __restrict__ W,
                       const float* __restrict__ dis, float* __restrict__ g, int N) {
    __shared__ float xs[4][C];
    int n0 = blockIdx.x * 4;
    int o = threadIdx.x;  // 0..127
    for (int nd = 0; nd < 4; ++nd) {
        int n = n0 + nd;
        xs[nd][o] = (n < N) ? x[(size_t)n * C + o] : 0.0f;
    }
    __syncthreads();
    float a0 = 0.f, a1 = 0.f, a2 = 0.f, a3 = 0.f;
    const float4* Wr = (const float4*)(W + (size_t)o * C);
#pragma unroll
    for (int i = 0; i < C / 4; ++i) {
        float4 w = Wr[i];
        int ib = i * 4;
        a0 += w.x * xs[0][ib] + w.y * xs[0][ib + 1] + w.z * xs[0][ib + 2] + w.w * xs[0][ib + 3];
        a1 += w.x * xs[1][ib] + w.y * xs[1][ib + 1] + w.z * xs[1][ib + 2] + w.w * xs[1][ib + 3];
        a2 += w.x * xs[2][ib] + w.y * xs[2][ib + 1] + w.z * xs[2][ib + 2] + w.w * xs[2][ib + 3];
        a3 += w.x * xs[3][ib] + w.y * xs[3][ib + 1] + w.z * xs[3][ib + 2] + w.w * xs[3][ib + 3];
    }
    float acc[4] = {a0, a1, a2, a3};
    for (int nd = 0; nd < 4; ++nd) {
        int n = n0 + nd;
        if (n < N) g[(size_t)n * C + o] = acc[nd] * dis[n];
    }
}

// ---- scatter: out[col[e]] += g[row[e]]  (32 threads/edge, 4 ch each) ----
__global__ void k_scatter(const int* __restrict__ row, const int* __restrict__ col,
                          const float* __restrict__ g, float* __restrict__ out, int E) {
    int t = blockIdx.x * blockDim.x + threadIdx.x;
    int e = t >> 5;
    if (e >= E) return;
    int c = (t & 31) << 2;
    int r = row[e];
    int d = col[e];
    float4 v = *(const float4*)(g + (size_t)r * C + c);
    float* o = out + (size_t)d * C + c;
    unsafeAtomicAdd(o + 0, v.x);
    unsafeAtomicAdd(o + 1, v.y);
    unsafeAtomicAdd(o + 2, v.z);
    unsafeAtomicAdd(o + 3, v.w);
}

// ---- out[v][c] = dis[v] * (g[v][c] + out[v][c]) + b[c] ----
// (the g[v] term is the self-loop: h[v]*dis[v]^2)
__global__ void k_final(float* __restrict__ out, const float* __restrict__ g,
                        const float* __restrict__ dis, const float* __restrict__ b, int total) {
    int idx = blockIdx.x * blockDim.x + threadIdx.x;
    if (idx >= total) return;
    int v = idx >> 7;        // /128
    int c = idx & (C - 1);
    out[idx] = dis[v] * (g[idx] + out[idx]) + b[c];
}

extern "C" void kernel_launch(void* const* d_in, const int* in_sizes, int n_in,
                              void* d_out, int out_size, void* d_ws, size_t ws_size,
                              hipStream_t stream) {
    const float* x  = (const float*)d_in[0];
    const int*   ei = (const int*)d_in[1];
    const float* W  = (const float*)d_in[2];
    const float* b  = (const float*)d_in[3];
    float* out = (float*)d_out;

    const int N = in_sizes[0] / C;   // 10000
    const int E = in_sizes[1] / 2;   // 640000
    const int* row = ei;             // edge_index[0]
    const int* col = ei + E;         // edge_index[1]

    // workspace layout: [dis: N floats (16B-align-padded)] [g: N*C floats]
    float* dis = (float*)d_ws;
    float* g   = dis + (((size_t)N + 3) & ~(size_t)3);

    // out doubles as the scatter accumulator; harness poisons it -> zero it.
    hipMemsetAsync(out, 0, (size_t)N * C * sizeof(float), stream);

    k_init_deg<<<(N + 255) / 256, 256, 0, stream>>>(dis, N);
    k_edge_deg<<<(E + 255) / 256, 256, 0, stream>>>(col, dis, E);
    k_dis<<<(N + 255) / 256, 256, 0, stream>>>(dis, N);
    k_gemm<<<(N + 3) / 4, C, 0, stream>>>(x, W, dis, g, N);
    k_scatter<<<(E * 32 + 255) / 256, 256, 0, stream>>>(row, col, g, out, E);
    k_final<<<(N * C + 255) / 256, 256, 0, stream>>>(out, g, dis, b, N * C);
}

// Round 2
// 223.243 us; speedup vs baseline: 5.6380x; 5.6380x over previous
//
#include <hip/hip_runtime.h>

#define C 128

// ---- pass 1: in-degree count per destination (i32 atomics) ----
__global__ void k_count(const int* __restrict__ col, int* __restrict__ counts, int E) {
    int e = blockIdx.x * blockDim.x + threadIdx.x;
    if (e < E) atomicAdd(&counts[col[e]], 1);
}

// ---- pass 2: single-block exclusive scan over counts -> offsets/cursor; dis = 1/sqrt(deg+1) ----
__global__ __launch_bounds__(1024) void k_scan(const int* __restrict__ counts,
                                               int* __restrict__ offsets,
                                               int* __restrict__ cursor,
                                               float* __restrict__ dis, int N) {
    __shared__ int sums[1024];
    int t = threadIdx.x;
    int items = (N + 1023) >> 10;
    int lo = t * items;
    int hi = min(N, lo + items);
    int s = 0;
    for (int i = lo; i < hi; ++i) s += counts[i];
    sums[t] = s;
    __syncthreads();
    // Hillis-Steele inclusive scan over the 1024 partial sums
    for (int off = 1; off < 1024; off <<= 1) {
        int v = (t >= off) ? sums[t - off] : 0;
        __syncthreads();
        sums[t] += v;
        __syncthreads();
    }
    int run = (t > 0) ? sums[t - 1] : 0;  // exclusive base
    for (int i = lo; i < hi; ++i) {
        offsets[i] = run;
        cursor[i] = run;
        dis[i] = 1.0f / sqrtf((float)(counts[i] + 1));  // +1 self loop
        run += counts[i];
    }
    if (t == 1023) offsets[N] = sums[1023];
}

// ---- pass 3: bucket source indices by destination ----
__global__ void k_fill(const int* __restrict__ row, const int* __restrict__ col,
                       int* __restrict__ cursor, int* __restrict__ srcIdx, int E) {
    int e = blockIdx.x * blockDim.x + threadIdx.x;
    if (e < E) {
        int d = col[e];
        int pos = atomicAdd(&cursor[d], 1);
        srcIdx[pos] = row[e];
    }
}

// ---- g[n][o] = (x[n] . W[o]) * dis[n]; 16 nodes per 128-thread block ----
#define NPB 16
__global__ __launch_bounds__(128) void k_gemm(const float* __restrict__ x,
                                              const float* __restrict__ W,
                                              const float* __restrict__ dis,
                                              float* __restrict__ g, int N) {
    __shared__ float xs[NPB][C];
    int n0 = blockIdx.x * NPB;
    int o = threadIdx.x;  // 0..127: output channel
    for (int nd = 0; nd < NPB; ++nd) {
        int n = n0 + nd;
        xs[nd][o] = (n < N) ? x[(size_t)n * C + o] : 0.0f;
    }
    __syncthreads();
    float acc[NPB];
#pragma unroll
    for (int nd = 0; nd < NPB; ++nd) acc[nd] = 0.0f;
    const float4* Wr = (const float4*)(W + (size_t)o * C);
#pragma unroll 8
    for (int i = 0; i < C / 4; ++i) {
        float4 w = Wr[i];
        int ib = i * 4;
#pragma unroll
        for (int nd = 0; nd < NPB; ++nd)
            acc[nd] += w.x * xs[nd][ib] + w.y * xs[nd][ib + 1] +
                       w.z * xs[nd][ib + 2] + w.w * xs[nd][ib + 3];
    }
    for (int nd = 0; nd < NPB; ++nd) {
        int n = n0 + nd;
        if (n < N) g[(size_t)n * C + o] = acc[nd] * dis[n];
    }
}

// ---- pass 4: wave per destination; register accumulation, no atomics ----
// lane L handles channels [2L, 2L+1]; self-loop fused; out = dis*acc + b
__global__ __launch_bounds__(256) void k_agg(const int* __restrict__ offsets,
                                             const int* __restrict__ srcIdx,
                                             const float* __restrict__ g,
                                             const float* __restrict__ dis,
                                             const float* __restrict__ b,
                                             float* __restrict__ out, int N) {
    int wave = (blockIdx.x * blockDim.x + threadIdx.x) >> 6;
    if (wave >= N) return;
    int lane = threadIdx.x & 63;
    int c = lane * 2;
    int d = wave;
    float2 acc = *(const float2*)(g + (size_t)d * C + c);  // self loop term
    int beg = offsets[d], end = offsets[d + 1];
    int j = beg;
    for (; j + 4 <= end; j += 4) {
        int s0 = srcIdx[j], s1 = srcIdx[j + 1], s2 = srcIdx[j + 2], s3 = srcIdx[j + 3];
        float2 v0 = *(const float2*)(g + (size_t)s0 * C + c);
        float2 v1 = *(const float2*)(g + (size_t)s1 * C + c);
        float2 v2 = *(const float2*)(g + (size_t)s2 * C + c);
        float2 v3 = *(const float2*)(g + (size_t)s3 * C + c);
        acc.x += (v0.x + v1.x) + (v2.x + v3.x);
        acc.y += (v0.y + v1.y) + (v2.y + v3.y);
    }
    for (; j < end; ++j) {
        int s = srcIdx[j];
        float2 v = *(const float2*)(g + (size_t)s * C + c);
        acc.x += v.x;
        acc.y += v.y;
    }
    float dv = dis[d];
    float2 bb = *(const float2*)(b + c);
    float2 o;
    o.x = dv * acc.x + bb.x;
    o.y = dv * acc.y + bb.y;
    *(float2*)(out + (size_t)d * C + c) = o;
}

extern "C" void kernel_launch(void* const* d_in, const int* in_sizes, int n_in,
                              void* d_out, int out_size, void* d_ws, size_t ws_size,
                              hipStream_t stream) {
    const float* x  = (const float*)d_in[0];
    const int*   ei = (const int*)d_in[1];
    const float* W  = (const float*)d_in[2];
    const float* b  = (const float*)d_in[3];
    float* out = (float*)d_out;

    const int N = in_sizes[0] / C;   // 10000
    const int E = in_sizes[1] / 2;   // 640000
    const int* row = ei;             // edge_index[0] (sources)
    const int* col = ei + E;         // edge_index[1] (destinations)

    // workspace layout (all 4B elems, 16B-aligned sections)
    size_t Na = ((size_t)N + 3) & ~(size_t)3;        // 10000
    size_t Na1 = ((size_t)N + 1 + 3) & ~(size_t)3;   // 10004
    int*   counts  = (int*)d_ws;                     // N
    int*   offsets = counts + Na;                    // N+1
    int*   cursor  = offsets + Na1;                  // N
    float* dis     = (float*)(cursor + Na);          // N
    int*   srcIdx  = (int*)(dis + Na);               // E
    float* g       = (float*)(srcIdx + (((size_t)E + 3) & ~(size_t)3));  // N*C

    hipMemsetAsync(counts, 0, (size_t)N * sizeof(int), stream);
    k_count<<<(E + 255) / 256, 256, 0, stream>>>(col, counts, E);
    k_scan<<<1, 1024, 0, stream>>>(counts, offsets, cursor, dis, N);
    k_fill<<<(E + 255) / 256, 256, 0, stream>>>(row, col, cursor, srcIdx, E);
    k_gemm<<<(N + NPB - 1) / NPB, 128, 0, stream>>>(x, W, dis, g, N);
    k_agg<<<((size_t)N * 64 + 255) / 256, 256, 0, stream>>>(offsets, srcIdx, g, dis, b, out, N);
}